// Round 17
// baseline (296.987 us; speedup 1.0000x reference)
//
#include <hip/hip_runtime.h>
#include <hip/hip_bf16.h>

#define N_NODES 50000
#define N_EDGES 800000
#define E_TOT   850000   // edges + self loops
#define N_GRAPHS 64
#define HID 512
#define NBC 196          // ceil(N_NODES/256)
#define PB  304          // prep blocks
#define EB  3321         // ceil(E_TOT/256)
#define WB  12500        // wave-per-node blocks (N_NODES*64/256)
#define WB2 6250         // 2-nodes-per-wave blocks (N_NODES*32/256)

typedef unsigned short u16;
typedef __attribute__((ext_vector_type(8))) short short8;
typedef __attribute__((ext_vector_type(4))) float floatx4;
typedef union { uint4 u; short8 s; } frag_u;

__device__ inline unsigned f2b(float x) {        // f32 -> bf16 bits (RNE)
    unsigned u = __float_as_uint(x);
    return (u + 0x7fffu + ((u >> 16) & 1u)) >> 16;
}
__device__ inline float b2f_lo(unsigned u) { return __uint_as_float(u << 16); }
__device__ inline float b2f_hi(unsigned u) { return __uint_as_float(u & 0xffff0000u); }

// ---------------------------------------------------------------- prep descriptor
struct PrepDesc {
    const float* W[3];
    const float* att[3];
    float* wsd[3];
    u16* Wt[3];
};

// ---------------------------------------------------------------- dispatch 1: prep (att-fold + Wt) + CSR count/rank
__global__ __launch_bounds__(256) void prep_count_kernel(PrepDesc d,
                                                         const int* __restrict__ dst_e,
                                                         int* __restrict__ cnt,
                                                         int* __restrict__ order) {
    const int DIN[3]  = {64, 64, 128};
    const int DOUT[3] = {64, 128, 256};
    int b = blockIdx.x;
    if (b >= PB) {
        // CSR pass 1: per-dst count + per-edge rank
        int e = (b - PB) * 256 + threadIdx.x;
        if (e >= E_TOT) return;
        int dd = (e < N_EDGES) ? dst_e[e] : (e - N_EDGES);
        order[e] = atomicAdd(&cnt[dd], 1);
        return;
    }
    if (b < 128) {
        // fold: wave per output element; 512 waves total
        int wg = (b * 256 + (int)threadIdx.x) >> 6;
        int lane = threadIdx.x & 63;
        int l = (wg < 128) ? 0 : (wg < 256) ? 1 : 2;
        int base = (l == 0) ? 0 : (l == 1) ? 128 : 256;
        int k = wg - base;
        int Din = DIN[l], Dout = DOUT[l];
        int half = (k >= Din) ? 1 : 0;
        int row = half ? (k - Din) : k;
        float s = 0.f;
        for (int j = lane; j < Dout; j += 64)
            s += d.W[l][(size_t)row * Dout + j] * d.att[l][half * Dout + j];
#pragma unroll
        for (int off = 32; off > 0; off >>= 1) s += __shfl_xor(s, off);
        if (lane == 0) d.wsd[l][k] = s;
    } else {
        // transpose to bf16: element per thread; 45056 elements total
        int t = (b - 128) * 256 + (int)threadIdx.x;
        int l; int off;
        if (t < 4096)       { l = 0; off = t; }
        else if (t < 12288) { l = 1; off = t - 4096; }
        else if (t < 45056) { l = 2; off = t - 12288; }
        else return;
        int Din = DIN[l], Dout = DOUT[l];
        int row = off / Dout, j = off & (Dout - 1);
        d.Wt[l][(size_t)j * Din + row] = (u16)f2b(d.W[l][off]);
    }
}

// ---------------------------------------------------------------- dispatch 2: block-local scan + feature cvt/lsld1
__global__ __launch_bounds__(256) void scan_cvt_kernel(const int* __restrict__ cnt,
                                                       int* __restrict__ row_ptr,      // partial (block-local excl)
                                                       int* __restrict__ blocksum,
                                                       const float* __restrict__ feature,
                                                       const float* __restrict__ wsd1,
                                                       u16* __restrict__ Fb,
                                                       float* __restrict__ lsld1) {
    if (blockIdx.x < NBC) {
        __shared__ int buf[256];
        int tid = threadIdx.x;
        int i = blockIdx.x * 256 + tid;
        int v = (i < N_NODES) ? cnt[i] : 0;
        buf[tid] = v;
        __syncthreads();
        for (int off = 1; off < 256; off <<= 1) {
            int t = (tid >= off) ? buf[tid - off] : 0;
            __syncthreads();
            buf[tid] += t;
            __syncthreads();
        }
        if (i < N_NODES) row_ptr[i] = buf[tid] - v;   // exclusive within block
        if (tid == 255) blocksum[blockIdx.x] = buf[255];
    } else {
        int wid = ((blockIdx.x - NBC) * 256 + (int)threadIdx.x) >> 6;
        int lane = threadIdx.x & 63;
        if (wid >= N_NODES) return;
        float h = feature[(size_t)wid * 64 + lane];
        float a0 = h * wsd1[lane];
        float a1 = h * wsd1[64 + lane];
#pragma unroll
        for (int off = 32; off > 0; off >>= 1) {
            a0 += __shfl_xor(a0, off);
            a1 += __shfl_xor(a1, off);
        }
        if (lane == 0) { lsld1[wid] = a0; lsld1[N_NODES + wid] = a1; }
        Fb[(size_t)wid * 64 + lane] = (u16)f2b(h);
    }
}

// ---------------------------------------------------------------- dispatch 3: row_ptr finalize + scatter fill
// Each block redoes the tiny 196-entry blocksum scan in LDS (L2-broadcast read).
// Race-free: fill reads the PARTIAL row_ptr; finalize writes the separate row_ptr2.
__global__ __launch_bounds__(256) void fin_fill_kernel(const int* __restrict__ edge_index,
                                                       const int* __restrict__ row_ptr,   // partial
                                                       const int* __restrict__ blocksum,
                                                       const int* __restrict__ order,
                                                       int* __restrict__ col_idx,
                                                       int* __restrict__ row_ptr2) {
    __shared__ int buf[256];
    __shared__ int boff[256];     // exclusive block offsets
    int tid = threadIdx.x;
    int v = (tid < NBC) ? blocksum[tid] : 0;
    buf[tid] = v;
    __syncthreads();
    for (int off = 1; off < 256; off <<= 1) {
        int t = (tid >= off) ? buf[tid - off] : 0;
        __syncthreads();
        buf[tid] += t;
        __syncthreads();
    }
    boff[tid] = buf[tid] - v;
    __syncthreads();

    if (blockIdx.x < NBC) {
        int i = blockIdx.x * 256 + tid;
        if (i < N_NODES) row_ptr2[i] = row_ptr[i] + boff[blockIdx.x];
        if (blockIdx.x == 0 && tid == NBC - 1) row_ptr2[N_NODES] = buf[tid];  // = E_TOT
        return;
    }
    int e = (blockIdx.x - NBC) * 256 + tid;
    if (e >= E_TOT) return;
    int s, d;
    if (e < N_EDGES) { s = edge_index[e]; d = edge_index[N_EDGES + e]; }
    else             { s = e - N_EDGES;   d = s; }
    col_idx[row_ptr[d] + boff[d >> 8] + order[e]] = s;
}

// ---------------------------------------------------------------- MFMA bf16 GEMM + bias + relu
// C[M,NN] = relu(A[M,KK] @ Bt^T + bias), A/Bt/C bf16 (Bt = [NN,KK]).
// Block: 128 rows x 64 cols; wave: 2 m-tiles x 4 n-tiles. Grid: ((M+127)/128, NN/64).
// Epilogue modes:
//  - wsd_next != nullptr: atomicAdd row dots into lsld_next (layers 1,2)
//  - gsum_pool != nullptr: fused mean-pool numerator (sorted batch) - C NOT written (layer 3)
//  - else: C written via LDS staging -> full-line dwordx4 stores
template <int NN, int KK>
__global__ __launch_bounds__(256) void sgemm_mfma_kernel(const u16* __restrict__ A,
                                                         const u16* __restrict__ Bt,
                                                         u16* __restrict__ C,
                                                         const float* __restrict__ bias,
                                                         const float* __restrict__ wsd_next,
                                                         float* __restrict__ lsld_next,
                                                         const int* __restrict__ batch,
                                                         float* __restrict__ gsum_pool,
                                                         int M) {
    constexpr int NT = 4;
    constexpr int KSTEPS = KK / 32;
    constexpr int CS = 72;           // LDS row stride (u16): 144 B, 16B-aligned
    __shared__ u16 cst[4][32 * CS];
    const int lane = threadIdx.x & 63;
    const int w = threadIdx.x >> 6;
    const int c = lane & 15;
    const int q = lane >> 4;
    const int bn = blockIdx.y * 64;
    const int r0 = blockIdx.x * 128 + w * 32;
    int ar0 = r0 + c;      if (ar0 > M - 1) ar0 = M - 1;
    int ar1 = r0 + 16 + c; if (ar1 > M - 1) ar1 = M - 1;
    const u16* __restrict__ Ap0 = A + (size_t)ar0 * KK + q * 8;
    const u16* __restrict__ Ap1 = A + (size_t)ar1 * KK + q * 8;
    floatx4 acc[2][NT];
#pragma unroll
    for (int i = 0; i < 2; ++i)
#pragma unroll
        for (int b = 0; b < NT; ++b) acc[i][b] = (floatx4){0.f, 0.f, 0.f, 0.f};
#pragma unroll
    for (int ks = 0; ks < KSTEPS; ++ks) {
        const int k0 = ks * 32;
        frag_u a0, a1, bf[NT];
        a0.u = *(const uint4*)(Ap0 + k0);
        a1.u = *(const uint4*)(Ap1 + k0);
#pragma unroll
        for (int b = 0; b < NT; ++b)
            bf[b].u = *(const uint4*)(Bt + (size_t)(bn + b * 16 + c) * KK + q * 8 + k0);
#pragma unroll
        for (int b = 0; b < NT; ++b) {
            acc[0][b] = __builtin_amdgcn_mfma_f32_16x16x32_bf16(a0.s, bf[b].s, acc[0][b], 0, 0, 0);
            acc[1][b] = __builtin_amdgcn_mfma_f32_16x16x32_bf16(a1.s, bf[b].s, acc[1][b], 0, 0, 0);
        }
    }

    if (gsum_pool) {
        // fused mean-pool numerator; batch sorted ascending. C/D: col=lane&15, row=quad*4+reg
        float bsv[NT];
#pragma unroll
        for (int b = 0; b < NT; ++b) bsv[b] = bias[bn + b * 16 + c];
        const bool full = (r0 + 31 < M);
        const int rl = full ? (r0 + 31) : (M - 1);
        if (full && batch[r0] == batch[rl]) {
            const int gr = batch[r0];
#pragma unroll
            for (int b = 0; b < NT; ++b) {
                float s = 0.f;
#pragma unroll
                for (int i = 0; i < 2; ++i)
#pragma unroll
                    for (int g = 0; g < 4; ++g) s += fmaxf(acc[i][b][g] + bsv[b], 0.f);
                s += __shfl_xor(s, 16);
                s += __shfl_xor(s, 32);
                if (q == 0) atomicAdd(&gsum_pool[gr * 256 + bn + b * 16 + c], s);
            }
        } else {
#pragma unroll
            for (int i = 0; i < 2; ++i) {
                int curg = -1;
                float sb[NT] = {0.f, 0.f, 0.f, 0.f};
#pragma unroll
                for (int g = 0; g < 4; ++g) {
                    int r = r0 + i * 16 + q * 4 + g;
                    if (r < M) {
                        int gr = batch[r];
                        if (gr != curg) {
                            if (curg >= 0) {
#pragma unroll
                                for (int b = 0; b < NT; ++b) {
                                    atomicAdd(&gsum_pool[curg * 256 + bn + b * 16 + c], sb[b]);
                                    sb[b] = 0.f;
                                }
                            }
                            curg = gr;
                        }
#pragma unroll
                        for (int b = 0; b < NT; ++b) sb[b] += fmaxf(acc[i][b][g] + bsv[b], 0.f);
                    }
                }
                if (curg >= 0) {
#pragma unroll
                    for (int b = 0; b < NT; ++b)
                        atomicAdd(&gsum_pool[curg * 256 + bn + b * 16 + c], sb[b]);
                }
            }
        }
        return;
    }

    const bool has_next = (wsd_next != nullptr);
    u16* __restrict__ cb = cst[w];
    float ps[2][4] = {}, pd[2][4] = {};
#pragma unroll
    for (int b = 0; b < NT; ++b) {
        const int col = bn + b * 16 + c;
        const float bsv = bias[col];
        const float wsv = has_next ? wsd_next[col] : 0.f;
        const float wdv = has_next ? wsd_next[NN + col] : 0.f;
#pragma unroll
        for (int i = 0; i < 2; ++i) {
#pragma unroll
            for (int g = 0; g < 4; ++g) {
                float v = fmaxf(acc[i][b][g] + bsv, 0.f);   // C/D: col=lane&15, row=quad*4+reg
                cb[(i * 16 + q * 4 + g) * CS + b * 16 + c] = (u16)f2b(v);
                ps[i][g] += v * wsv;
                pd[i][g] += v * wdv;
            }
        }
    }
    if (has_next) {
#pragma unroll
        for (int i = 0; i < 2; ++i)
#pragma unroll
            for (int g = 0; g < 4; ++g) {
#pragma unroll
                for (int mm = 1; mm < 16; mm <<= 1) {
                    ps[i][g] += __shfl_xor(ps[i][g], mm);
                    pd[i][g] += __shfl_xor(pd[i][g], mm);
                }
            }
        if (c == 0) {
#pragma unroll
            for (int i = 0; i < 2; ++i)
#pragma unroll
                for (int g = 0; g < 4; ++g) {
                    int r = r0 + i * 16 + q * 4 + g;
                    if (r < M) {
                        atomicAdd(&lsld_next[r], ps[i][g]);
                        atomicAdd(&lsld_next[M + r], pd[i][g]);
                    }
                }
        }
    }
    // wave-synchronous LDS readback -> 16B vector stores (8 lanes cover a 128B row)
#pragma unroll
    for (int p = 0; p < 4; ++p) {
        int lr = p * 8 + (lane >> 3);
        int r = r0 + lr;
        if (r < M) {
            uint4 val = *(const uint4*)&cb[lr * CS + (lane & 7) * 8];
            *(uint4*)(C + (size_t)r * NN + bn + (lane & 7) * 8) = val;
        }
    }
}

// ---------------------------------------------------------------- D=64 gather: 2 nodes per wave (32-lane halves)
// softmax over 32 lanes per node; 4 edge-slots of 8 lanes; single 8-deep predicated pass (deg<=32)
__global__ __launch_bounds__(256) void gather2_kernel(const u16* __restrict__ X,
                                                      const float* __restrict__ lsld,
                                                      const int* __restrict__ row_ptr,
                                                      const int* __restrict__ col_idx,
                                                      u16* __restrict__ out) {
    __shared__ float2 ec_all[4][64];
    int gw = (blockIdx.x * 256 + threadIdx.x) >> 6;   // wave id (0..24999)
    int lane = threadIdx.x & 63;
    int half = lane >> 5;
    int hl = lane & 31;
    int nid = gw * 2 + half;
    if (nid >= N_NODES) return;
    float2* __restrict__ ec = ec_all[threadIdx.x >> 6] + half * 32;
    const int start = row_ptr[nid];
    const int end = row_ptr[nid + 1];
    const int deg = end - start;
    const float ldi = lsld[N_NODES + nid];
    const float* __restrict__ ls = lsld;
    const int eslot = hl >> 3;   // 0..3
    const int fidx = hl & 7;
    float a[8] = {0.f, 0.f, 0.f, 0.f, 0.f, 0.f, 0.f, 0.f};

    auto fma8 = [&](float cc, uint4 v) {
        a[0] += cc * b2f_lo(v.x); a[1] += cc * b2f_hi(v.x);
        a[2] += cc * b2f_lo(v.y); a[3] += cc * b2f_hi(v.y);
        a[4] += cc * b2f_lo(v.z); a[5] += cc * b2f_hi(v.z);
        a[6] += cc * b2f_lo(v.w); a[7] += cc * b2f_hi(v.w);
    };

    if (deg <= 32) {
        // softmax in registers (edge ordinal == hl), stage (coef, src) to LDS
        int srcl = 0;
        float l = -3.0e38f;
        if (hl < deg) {
            srcl = col_idx[start + hl];
            float t = ls[srcl] + ldi;
            l = (t > 0.f) ? t : 0.2f * t;
        }
        float m = l;
#pragma unroll
        for (int off = 16; off > 0; off >>= 1) m = fmaxf(m, __shfl_xor(m, off));
        float e = (hl < deg) ? __expf(l - m) : 0.f;
        float s = e;
#pragma unroll
        for (int off = 16; off > 0; off >>= 1) s += __shfl_xor(s, off);
        ec[hl] = make_float2(e / s, __int_as_float(srcl));
        // wave-synchronous: ds_write -> ds_read ordered within the wave

        // single fully-unrolled 8-deep pass: covers deg<=32 (8 steps x 4 slots), 8 loads in flight
        float2 p[8]; uint4 v[8];
#pragma unroll
        for (int j = 0; j < 8; ++j) {
            int idx = j * 4 + eslot;
            bool valid = idx < deg;
            p[j] = ec[valid ? idx : 0];
            if (!valid) p[j].x = 0.f;
        }
#pragma unroll
        for (int j = 0; j < 8; ++j)
            v[j] = *(const uint4*)(X + (size_t)__float_as_int(p[j].y) * 64 + fidx * 8);
#pragma unroll
        for (int j = 0; j < 8; ++j) fma8(p[j].x, v[j]);
    } else {
        // deg > 32: strided 32-lane passes, recompute coef during gather
        float m = -3.0e38f;
        for (int e = start + hl; e < end; e += 32) {
            float t = ls[col_idx[e]] + ldi;
            t = (t > 0.f) ? t : 0.2f * t;
            m = fmaxf(m, t);
        }
#pragma unroll
        for (int off = 16; off > 0; off >>= 1) m = fmaxf(m, __shfl_xor(m, off));
        float ssum = 0.f;
        for (int e = start + hl; e < end; e += 32) {
            float t = ls[col_idx[e]] + ldi;
            t = (t > 0.f) ? t : 0.2f * t;
            ssum += __expf(t - m);
        }
#pragma unroll
        for (int off = 16; off > 0; off >>= 1) ssum += __shfl_xor(ssum, off);
        const float inv = 1.0f / ssum;
        for (int e0 = start; e0 < end; e0 += 4) {
            int e = e0 + eslot;
            if (e < end) {
                int src = col_idx[e];
                float t = ls[src] + ldi;
                t = (t > 0.f) ? t : 0.2f * t;
                float cc = __expf(t - m) * inv;
                uint4 v = *(const uint4*)(X + (size_t)src * 64 + fidx * 8);
                fma8(cc, v);
            }
        }
    }
    // reduce across the 4 edge slots (xor 8, 16 stay within the 32-half)
#pragma unroll
    for (int mm = 8; mm < 32; mm <<= 1) {
#pragma unroll
        for (int i = 0; i < 8; ++i) a[i] += __shfl_xor(a[i], mm);
    }
    if (hl < 8) {
        uint4 o;
        o.x = f2b(a[0]) | (f2b(a[1]) << 16);
        o.y = f2b(a[2]) | (f2b(a[3]) << 16);
        o.z = f2b(a[4]) | (f2b(a[5]) << 16);
        o.w = f2b(a[6]) | (f2b(a[7]) << 16);
        *(uint4*)(out + (size_t)nid * 64 + hl * 8) = o;
    }
}

// ---------------------------------------------------------------- D=128 gather (wave per node, 8-deep predicated)
template <int D>
__global__ __launch_bounds__(256) void gather_fused_kernel(const u16* __restrict__ X,
                                                           const float* __restrict__ lsld,
                                                           const int* __restrict__ row_ptr,
                                                           const int* __restrict__ col_idx,
                                                           u16* __restrict__ out) {
    constexpr int L = D / 8;     // lanes per edge (16B = 8 bf16 each)
    constexpr int P = 64 / L;    // edges handled concurrently by one wave
    __shared__ float2 ec_all[4][64];
    int wid = (blockIdx.x * 256 + threadIdx.x) >> 6;
    int lane = threadIdx.x & 63;
    if (wid >= N_NODES) return;
    float2* __restrict__ ec = ec_all[threadIdx.x >> 6];
    const int start = row_ptr[wid];
    const int end = row_ptr[wid + 1];
    const int deg = end - start;
    const float ldi = lsld[N_NODES + wid];
    const float* __restrict__ ls = lsld;
    const int eslot = lane / L;
    const int fidx = lane % L;
    float a[8] = {0.f, 0.f, 0.f, 0.f, 0.f, 0.f, 0.f, 0.f};

    auto fma8 = [&](float cc, uint4 v) {
        a[0] += cc * b2f_lo(v.x); a[1] += cc * b2f_hi(v.x);
        a[2] += cc * b2f_lo(v.y); a[3] += cc * b2f_hi(v.y);
        a[4] += cc * b2f_lo(v.z); a[5] += cc * b2f_hi(v.z);
        a[6] += cc * b2f_lo(v.w); a[7] += cc * b2f_hi(v.w);
    };

    if (deg <= 64) {
        int srcl = 0;
        float l = -3.0e38f;
        if (lane < deg) {
            srcl = col_idx[start + lane];
            float t = ls[srcl] + ldi;
            l = (t > 0.f) ? t : 0.2f * t;
        }
        float m = l;
#pragma unroll
        for (int off = 32; off > 0; off >>= 1) m = fmaxf(m, __shfl_xor(m, off));
        float e = (lane < deg) ? __expf(l - m) : 0.f;
        float s = e;
#pragma unroll
        for (int off = 32; off > 0; off >>= 1) s += __shfl_xor(s, off);
        ec[lane] = make_float2(e / s, __int_as_float(srcl));
        // wave-synchronous: ds_write -> ds_read ordered within the wave

        // 8-deep predicated chunks: 8 loads in flight (deg >= 1 from self-loop)
        const int nsteps = (deg + P - 1) / P;
        for (int g0 = 0; g0 < nsteps; g0 += 8) {
            float2 p[8]; uint4 v[8];
#pragma unroll
            for (int j = 0; j < 8; ++j) {
                int idx = (g0 + j) * P + eslot;
                bool valid = idx < deg;
                p[j] = ec[valid ? idx : 0];
                if (!valid) p[j].x = 0.f;
            }
#pragma unroll
            for (int j = 0; j < 8; ++j)
                v[j] = *(const uint4*)(X + (size_t)__float_as_int(p[j].y) * D + fidx * 8);
#pragma unroll
            for (int j = 0; j < 8; ++j) fma8(p[j].x, v[j]);
        }
    } else {
        float m = -3.0e38f;
        for (int e = start + lane; e < end; e += 64) {
            float t = ls[col_idx[e]] + ldi;
            t = (t > 0.f) ? t : 0.2f * t;
            m = fmaxf(m, t);
        }
#pragma unroll
        for (int off = 32; off > 0; off >>= 1) m = fmaxf(m, __shfl_xor(m, off));
        float ssum = 0.f;
        for (int e = start + lane; e < end; e += 64) {
            float t = ls[col_idx[e]] + ldi;
            t = (t > 0.f) ? t : 0.2f * t;
            ssum += __expf(t - m);
        }
#pragma unroll
        for (int off = 32; off > 0; off >>= 1) ssum += __shfl_xor(ssum, off);
        const float inv = 1.0f / ssum;
        for (int e0 = start; e0 < end; e0 += P) {
            int e = e0 + eslot;
            if (e < end) {
                int src = col_idx[e];
                float t = ls[src] + ldi;
                t = (t > 0.f) ? t : 0.2f * t;
                float cc = __expf(t - m) * inv;
                uint4 v = *(const uint4*)(X + (size_t)src * D + fidx * 8);
                fma8(cc, v);
            }
        }
    }
#pragma unroll
    for (int mm = L; mm < 64; mm <<= 1) {
#pragma unroll
        for (int i = 0; i < 8; ++i) a[i] += __shfl_xor(a[i], mm);
    }
    if (lane < L) {
        uint4 o;
        o.x = f2b(a[0]) | (f2b(a[1]) << 16);
        o.y = f2b(a[2]) | (f2b(a[3]) << 16);
        o.z = f2b(a[4]) | (f2b(a[5]) << 16);
        o.w = f2b(a[6]) | (f2b(a[7]) << 16);
        *(uint4*)(out + (size_t)wid * D + lane * 8) = o;
    }
}

// ---------------------------------------------------------------- merged head MLP (gcnt + fc1 + fc2, f32)
__device__ inline int lower_bound_dev(const int* __restrict__ a, int n, int v) {
    int lo = 0, hi = n;
    while (lo < hi) { int mid = (lo + hi) >> 1; if (a[mid] < v) lo = mid + 1; else hi = mid; }
    return lo;
}

__global__ __launch_bounds__(256) void fc_kernel(const float* __restrict__ gsum,
                                                 const int* __restrict__ batch,
                                                 const float* __restrict__ w1,
                                                 const float* __restrict__ b1,
                                                 const float* __restrict__ w2,
                                                 const float* __restrict__ b2,
                                                 float* __restrict__ out) {
    __shared__ float gc[256];
    __shared__ float h1s[HID];
    __shared__ float red[256];
    __shared__ int s_cnt;
    int g = blockIdx.x;
    int tid = threadIdx.x;
    if (tid == 0)
        s_cnt = lower_bound_dev(batch, N_NODES, g + 1) - lower_bound_dev(batch, N_NODES, g);
    __syncthreads();
    float denom = fmaxf((float)s_cnt, 1.0f);
    gc[tid] = gsum[g * 256 + tid] / denom;
    __syncthreads();
#pragma unroll
    for (int jj = 0; jj < 2; ++jj) {
        int j = tid + jj * 256;
        float sum = b1[j];
        for (int k = 0; k < 256; ++k) sum += gc[k] * w1[k * HID + j];
        h1s[j] = (sum > 0.f) ? sum : 0.f;
    }
    __syncthreads();
    float acc = h1s[tid] * w2[tid] + h1s[tid + 256] * w2[tid + 256];
    red[tid] = acc;
    __syncthreads();
    for (int off = 128; off > 0; off >>= 1) {
        if (tid < off) red[tid] += red[tid + off];
        __syncthreads();
    }
    if (tid == 0) out[g] = red[0] + b2[0];
}

// ---------------------------------------------------------------- launch
extern "C" void kernel_launch(void* const* d_in, const int* in_sizes, int n_in,
                              void* d_out, int out_size, void* d_ws, size_t ws_size,
                              hipStream_t stream) {
    const float* feature  = (const float*)d_in[0];
    const int*   edge_idx = (const int*)d_in[1];
    const int*   batch    = (const int*)d_in[2];
    const float* W1    = (const float*)d_in[3];
    const float* att1  = (const float*)d_in[4];
    const float* b1    = (const float*)d_in[5];
    const float* W2    = (const float*)d_in[6];
    const float* att2  = (const float*)d_in[7];
    const float* b2    = (const float*)d_in[8];
    const float* W3    = (const float*)d_in[9];
    const float* att3  = (const float*)d_in[10];
    const float* b3    = (const float*)d_in[11];
    const float* fc1_w = (const float*)d_in[12];
    const float* fc1_b = (const float*)d_in[13];
    const float* fc2_w = (const float*)d_in[14];
    const float* fc2_b = (const float*)d_in[15];
    float* out = (float*)d_out;

    char* w = (char*)d_ws;
    auto alloc = [&](size_t bytes) {
        char* p = w;
        w += (bytes + 255) & ~(size_t)255;
        return p;
    };
    u16* Fb    = (u16*)alloc((size_t)N_NODES * 64 * 2);
    u16* X1b   = (u16*)alloc((size_t)N_NODES * 64 * 2);
    u16* X2b   = (u16*)alloc((size_t)N_NODES * 128 * 2);
    u16* AGGb  = (u16*)alloc((size_t)N_NODES * 128 * 2);
    float* lsld1 = (float*)alloc((size_t)N_NODES * 2 * 4);
    // ---- contiguous zero region: cnt | gsum | lsld2 | lsld3 ----
    char* zbase = w;
    int* cnt      = (int*)alloc((size_t)N_NODES * 4);
    float* gsum   = (float*)alloc(64 * 256 * 4);
    float* lsld23 = (float*)alloc((size_t)N_NODES * 4 * 4);
    size_t zbytes = (size_t)(w - zbase);
    float* lsld2 = lsld23;
    float* lsld3 = lsld23 + (size_t)N_NODES * 2;
    // ---------------------------------------------------------------
    float* wsd1  = (float*)alloc(2 * 64 * 4);
    float* wsd2  = (float*)alloc(2 * 64 * 4);
    float* wsd3  = (float*)alloc(2 * 128 * 4);
    u16* Wt1   = (u16*)alloc(64 * 64 * 2);     // [Dout,Din]
    u16* Wt2   = (u16*)alloc(128 * 64 * 2);
    u16* Wt3   = (u16*)alloc(256 * 128 * 2);
    int* row_ptr  = (int*)alloc((size_t)N_NODES * 4);        // partial (block-local)
    int* row_ptr2 = (int*)alloc((size_t)(N_NODES + 1) * 4);  // finalized
    int* col_idx  = (int*)alloc((size_t)E_TOT * 4);
    int* order    = (int*)alloc((size_t)E_TOT * 4);
    int* blocksum = (int*)alloc(256 * 4);

    hipMemsetAsync(zbase, 0, zbytes, stream);

    const int GB = (N_NODES + 127) / 128;        // MFMA GEMM row-blocks (391)

    PrepDesc pd;
    pd.W[0] = W1; pd.W[1] = W2; pd.W[2] = W3;
    pd.att[0] = att1; pd.att[1] = att2; pd.att[2] = att3;
    pd.wsd[0] = wsd1; pd.wsd[1] = wsd2; pd.wsd[2] = wsd3;
    pd.Wt[0] = Wt1; pd.Wt[1] = Wt2; pd.Wt[2] = Wt3;

    // D1: prep + CSR count (independent halves)
    prep_count_kernel<<<PB + EB, 256, 0, stream>>>(pd, edge_idx + N_EDGES, cnt, order);
    // D2: block-local scan + feature cvt/lsld1 (independent halves)
    scan_cvt_kernel<<<NBC + WB, 256, 0, stream>>>(cnt, row_ptr, blocksum, feature, wsd1, Fb, lsld1);
    // D3: row_ptr finalize + scatter fill (per-block redundant blocksum scan)
    fin_fill_kernel<<<NBC + EB, 256, 0, stream>>>(edge_idx, row_ptr, blocksum, order, col_idx, row_ptr2);

    // ---- layer 1: Din=64 -> Dout=64
    gather2_kernel<<<WB2, 256, 0, stream>>>(Fb, lsld1, row_ptr2, col_idx, AGGb);
    sgemm_mfma_kernel<64, 64><<<dim3(GB, 1), 256, 0, stream>>>(AGGb, Wt1, X1b, b1, wsd2, lsld2, nullptr, nullptr, N_NODES);

    // ---- layer 2: Din=64 -> Dout=128
    gather2_kernel<<<WB2, 256, 0, stream>>>(X1b, lsld2, row_ptr2, col_idx, AGGb);
    sgemm_mfma_kernel<128, 64><<<dim3(GB, 2), 256, 0, stream>>>(AGGb, Wt2, X2b, b2, wsd3, lsld3, nullptr, nullptr, N_NODES);

    // ---- layer 3: Din=128 -> Dout=256, fused mean-pool numerator (no X3 materialization)
    gather_fused_kernel<128><<<WB, 256, 0, stream>>>(X2b, lsld3, row_ptr2, col_idx, AGGb);
    sgemm_mfma_kernel<256, 128><<<dim3(GB, 4), 256, 0, stream>>>(AGGb, Wt3, nullptr, b3, nullptr, nullptr, batch, gsum, N_NODES);

    // ---- merged head (gcnt + fc1 + fc2)
    fc_kernel<<<N_GRAPHS, 256, 0, stream>>>(gsum, batch, fc1_w, fc1_b, fc2_w, fc2_b, out);
}

// Round 18
// 289.086 us; speedup vs baseline: 1.0273x; 1.0273x over previous
//
#include <hip/hip_runtime.h>
#include <hip/hip_bf16.h>

#define N_NODES 50000
#define N_EDGES 800000
#define E_TOT   850000   // edges + self loops
#define N_GRAPHS 64
#define HID 512
#define NBC 196          // ceil(N_NODES/256)
#define PB  304          // prep blocks
#define EB  3321         // ceil(E_TOT/256)
#define WB  12500        // wave-per-node blocks (N_NODES*64/256)
#define WB2 6250         // 2-nodes-per-wave blocks (N_NODES*32/256)

typedef unsigned short u16;
typedef __attribute__((ext_vector_type(8))) short short8;
typedef __attribute__((ext_vector_type(4))) float floatx4;
typedef union { uint4 u; short8 s; } frag_u;

__device__ inline unsigned f2b(float x) {        // f32 -> bf16 bits (RNE)
    unsigned u = __float_as_uint(x);
    return (u + 0x7fffu + ((u >> 16) & 1u)) >> 16;
}
__device__ inline float b2f_lo(unsigned u) { return __uint_as_float(u << 16); }
__device__ inline float b2f_hi(unsigned u) { return __uint_as_float(u & 0xffff0000u); }

// ---------------------------------------------------------------- prep descriptor
struct PrepDesc {
    const float* W[3];
    const float* att[3];
    float* wsd[3];
    u16* Wt[3];
};

// ---------------------------------------------------------------- dispatch 1: prep (att-fold + Wt) + CSR count/rank
__global__ __launch_bounds__(256) void prep_count_kernel(PrepDesc d,
                                                         const int* __restrict__ dst_e,
                                                         int* __restrict__ cnt,
                                                         int* __restrict__ order) {
    const int DIN[3]  = {64, 64, 128};
    const int DOUT[3] = {64, 128, 256};
    int b = blockIdx.x;
    if (b >= PB) {
        // CSR pass 1: per-dst count + per-edge rank
        int e = (b - PB) * 256 + threadIdx.x;
        if (e >= E_TOT) return;
        int dd = (e < N_EDGES) ? dst_e[e] : (e - N_EDGES);
        order[e] = atomicAdd(&cnt[dd], 1);
        return;
    }
    if (b < 128) {
        // fold: wave per output element; 512 waves total
        int wg = (b * 256 + (int)threadIdx.x) >> 6;
        int lane = threadIdx.x & 63;
        int l = (wg < 128) ? 0 : (wg < 256) ? 1 : 2;
        int base = (l == 0) ? 0 : (l == 1) ? 128 : 256;
        int k = wg - base;
        int Din = DIN[l], Dout = DOUT[l];
        int half = (k >= Din) ? 1 : 0;
        int row = half ? (k - Din) : k;
        float s = 0.f;
        for (int j = lane; j < Dout; j += 64)
            s += d.W[l][(size_t)row * Dout + j] * d.att[l][half * Dout + j];
#pragma unroll
        for (int off = 32; off > 0; off >>= 1) s += __shfl_xor(s, off);
        if (lane == 0) d.wsd[l][k] = s;
    } else {
        // transpose to bf16: element per thread; 45056 elements total
        int t = (b - 128) * 256 + (int)threadIdx.x;
        int l; int off;
        if (t < 4096)       { l = 0; off = t; }
        else if (t < 12288) { l = 1; off = t - 4096; }
        else if (t < 45056) { l = 2; off = t - 12288; }
        else return;
        int Din = DIN[l], Dout = DOUT[l];
        int row = off / Dout, j = off & (Dout - 1);
        d.Wt[l][(size_t)j * Din + row] = (u16)f2b(d.W[l][off]);
    }
}

// ---------------------------------------------------------------- dispatch 2: block-local scan + feature cvt/lsld1
__global__ __launch_bounds__(256) void scan_cvt_kernel(const int* __restrict__ cnt,
                                                       int* __restrict__ row_ptr,      // partial (block-local excl)
                                                       int* __restrict__ blocksum,
                                                       const float* __restrict__ feature,
                                                       const float* __restrict__ wsd1,
                                                       u16* __restrict__ Fb,
                                                       float* __restrict__ lsld1) {
    if (blockIdx.x < NBC) {
        __shared__ int buf[256];
        int tid = threadIdx.x;
        int i = blockIdx.x * 256 + tid;
        int v = (i < N_NODES) ? cnt[i] : 0;
        buf[tid] = v;
        __syncthreads();
        for (int off = 1; off < 256; off <<= 1) {
            int t = (tid >= off) ? buf[tid - off] : 0;
            __syncthreads();
            buf[tid] += t;
            __syncthreads();
        }
        if (i < N_NODES) row_ptr[i] = buf[tid] - v;   // exclusive within block
        if (tid == 255) blocksum[blockIdx.x] = buf[255];
    } else {
        int wid = ((blockIdx.x - NBC) * 256 + (int)threadIdx.x) >> 6;
        int lane = threadIdx.x & 63;
        if (wid >= N_NODES) return;
        float h = feature[(size_t)wid * 64 + lane];
        float a0 = h * wsd1[lane];
        float a1 = h * wsd1[64 + lane];
#pragma unroll
        for (int off = 32; off > 0; off >>= 1) {
            a0 += __shfl_xor(a0, off);
            a1 += __shfl_xor(a1, off);
        }
        if (lane == 0) { lsld1[wid] = a0; lsld1[N_NODES + wid] = a1; }
        Fb[(size_t)wid * 64 + lane] = (u16)f2b(h);
    }
}

// ---------------------------------------------------------------- dispatch 3: row_ptr finalize + scatter fill
// Each block redoes the tiny 196-entry blocksum scan in LDS (L2-broadcast read).
// Race-free: fill reads the PARTIAL row_ptr; finalize writes the separate row_ptr2.
__global__ __launch_bounds__(256) void fin_fill_kernel(const int* __restrict__ edge_index,
                                                       const int* __restrict__ row_ptr,   // partial
                                                       const int* __restrict__ blocksum,
                                                       const int* __restrict__ order,
                                                       int* __restrict__ col_idx,
                                                       int* __restrict__ row_ptr2) {
    __shared__ int buf[256];
    __shared__ int boff[256];     // exclusive block offsets
    int tid = threadIdx.x;
    int v = (tid < NBC) ? blocksum[tid] : 0;
    buf[tid] = v;
    __syncthreads();
    for (int off = 1; off < 256; off <<= 1) {
        int t = (tid >= off) ? buf[tid - off] : 0;
        __syncthreads();
        buf[tid] += t;
        __syncthreads();
    }
    boff[tid] = buf[tid] - v;
    __syncthreads();

    if (blockIdx.x < NBC) {
        int i = blockIdx.x * 256 + tid;
        if (i < N_NODES) row_ptr2[i] = row_ptr[i] + boff[blockIdx.x];
        if (blockIdx.x == 0 && tid == NBC - 1) row_ptr2[N_NODES] = buf[tid];  // = E_TOT
        return;
    }
    int e = (blockIdx.x - NBC) * 256 + tid;
    if (e >= E_TOT) return;
    int s, d;
    if (e < N_EDGES) { s = edge_index[e]; d = edge_index[N_EDGES + e]; }
    else             { s = e - N_EDGES;   d = s; }
    col_idx[row_ptr[d] + boff[d >> 8] + order[e]] = s;
}

// ---------------------------------------------------------------- MFMA bf16 GEMM + bias + relu
// C[M,NN] = relu(A[M,KK] @ Bt^T + bias), A/Bt/C bf16 (Bt = [NN,KK]).
// Block: 128 rows x 64 cols; wave: 2 m-tiles x 4 n-tiles. Grid: ((M+127)/128, NN/64).
// Epilogue modes:
//  - wsd_next != nullptr: atomicAdd row dots into lsld_next (layers 1,2)
//  - gsum_pool != nullptr: fused mean-pool numerator (sorted batch) - C NOT written (layer 3)
//  - else: C written via LDS staging -> full-line dwordx4 stores
template <int NN, int KK>
__global__ __launch_bounds__(256) void sgemm_mfma_kernel(const u16* __restrict__ A,
                                                         const u16* __restrict__ Bt,
                                                         u16* __restrict__ C,
                                                         const float* __restrict__ bias,
                                                         const float* __restrict__ wsd_next,
                                                         float* __restrict__ lsld_next,
                                                         const int* __restrict__ batch,
                                                         float* __restrict__ gsum_pool,
                                                         int M) {
    constexpr int NT = 4;
    constexpr int KSTEPS = KK / 32;
    constexpr int CS = 72;           // LDS row stride (u16): 144 B, 16B-aligned
    __shared__ u16 cst[4][32 * CS];
    const int lane = threadIdx.x & 63;
    const int w = threadIdx.x >> 6;
    const int c = lane & 15;
    const int q = lane >> 4;
    const int bn = blockIdx.y * 64;
    const int r0 = blockIdx.x * 128 + w * 32;
    int ar0 = r0 + c;      if (ar0 > M - 1) ar0 = M - 1;
    int ar1 = r0 + 16 + c; if (ar1 > M - 1) ar1 = M - 1;
    const u16* __restrict__ Ap0 = A + (size_t)ar0 * KK + q * 8;
    const u16* __restrict__ Ap1 = A + (size_t)ar1 * KK + q * 8;
    floatx4 acc[2][NT];
#pragma unroll
    for (int i = 0; i < 2; ++i)
#pragma unroll
        for (int b = 0; b < NT; ++b) acc[i][b] = (floatx4){0.f, 0.f, 0.f, 0.f};
#pragma unroll
    for (int ks = 0; ks < KSTEPS; ++ks) {
        const int k0 = ks * 32;
        frag_u a0, a1, bf[NT];
        a0.u = *(const uint4*)(Ap0 + k0);
        a1.u = *(const uint4*)(Ap1 + k0);
#pragma unroll
        for (int b = 0; b < NT; ++b)
            bf[b].u = *(const uint4*)(Bt + (size_t)(bn + b * 16 + c) * KK + q * 8 + k0);
#pragma unroll
        for (int b = 0; b < NT; ++b) {
            acc[0][b] = __builtin_amdgcn_mfma_f32_16x16x32_bf16(a0.s, bf[b].s, acc[0][b], 0, 0, 0);
            acc[1][b] = __builtin_amdgcn_mfma_f32_16x16x32_bf16(a1.s, bf[b].s, acc[1][b], 0, 0, 0);
        }
    }

    if (gsum_pool) {
        // fused mean-pool numerator; batch sorted ascending. C/D: col=lane&15, row=quad*4+reg
        float bsv[NT];
#pragma unroll
        for (int b = 0; b < NT; ++b) bsv[b] = bias[bn + b * 16 + c];
        const bool full = (r0 + 31 < M);
        const int rl = full ? (r0 + 31) : (M - 1);
        if (full && batch[r0] == batch[rl]) {
            const int gr = batch[r0];
#pragma unroll
            for (int b = 0; b < NT; ++b) {
                float s = 0.f;
#pragma unroll
                for (int i = 0; i < 2; ++i)
#pragma unroll
                    for (int g = 0; g < 4; ++g) s += fmaxf(acc[i][b][g] + bsv[b], 0.f);
                s += __shfl_xor(s, 16);
                s += __shfl_xor(s, 32);
                if (q == 0) atomicAdd(&gsum_pool[gr * 256 + bn + b * 16 + c], s);
            }
        } else {
#pragma unroll
            for (int i = 0; i < 2; ++i) {
                int curg = -1;
                float sb[NT] = {0.f, 0.f, 0.f, 0.f};
#pragma unroll
                for (int g = 0; g < 4; ++g) {
                    int r = r0 + i * 16 + q * 4 + g;
                    if (r < M) {
                        int gr = batch[r];
                        if (gr != curg) {
                            if (curg >= 0) {
#pragma unroll
                                for (int b = 0; b < NT; ++b) {
                                    atomicAdd(&gsum_pool[curg * 256 + bn + b * 16 + c], sb[b]);
                                    sb[b] = 0.f;
                                }
                            }
                            curg = gr;
                        }
#pragma unroll
                        for (int b = 0; b < NT; ++b) sb[b] += fmaxf(acc[i][b][g] + bsv[b], 0.f);
                    }
                }
                if (curg >= 0) {
#pragma unroll
                    for (int b = 0; b < NT; ++b)
                        atomicAdd(&gsum_pool[curg * 256 + bn + b * 16 + c], sb[b]);
                }
            }
        }
        return;
    }

    const bool has_next = (wsd_next != nullptr);
    u16* __restrict__ cb = cst[w];
    float ps[2][4] = {}, pd[2][4] = {};
#pragma unroll
    for (int b = 0; b < NT; ++b) {
        const int col = bn + b * 16 + c;
        const float bsv = bias[col];
        const float wsv = has_next ? wsd_next[col] : 0.f;
        const float wdv = has_next ? wsd_next[NN + col] : 0.f;
#pragma unroll
        for (int i = 0; i < 2; ++i) {
#pragma unroll
            for (int g = 0; g < 4; ++g) {
                float v = fmaxf(acc[i][b][g] + bsv, 0.f);   // C/D: col=lane&15, row=quad*4+reg
                cb[(i * 16 + q * 4 + g) * CS + b * 16 + c] = (u16)f2b(v);
                ps[i][g] += v * wsv;
                pd[i][g] += v * wdv;
            }
        }
    }
    if (has_next) {
#pragma unroll
        for (int i = 0; i < 2; ++i)
#pragma unroll
            for (int g = 0; g < 4; ++g) {
#pragma unroll
                for (int mm = 1; mm < 16; mm <<= 1) {
                    ps[i][g] += __shfl_xor(ps[i][g], mm);
                    pd[i][g] += __shfl_xor(pd[i][g], mm);
                }
            }
        if (c == 0) {
#pragma unroll
            for (int i = 0; i < 2; ++i)
#pragma unroll
                for (int g = 0; g < 4; ++g) {
                    int r = r0 + i * 16 + q * 4 + g;
                    if (r < M) {
                        atomicAdd(&lsld_next[r], ps[i][g]);
                        atomicAdd(&lsld_next[M + r], pd[i][g]);
                    }
                }
        }
    }
    // wave-synchronous LDS readback -> 16B vector stores (8 lanes cover a 128B row)
#pragma unroll
    for (int p = 0; p < 4; ++p) {
        int lr = p * 8 + (lane >> 3);
        int r = r0 + lr;
        if (r < M) {
            uint4 val = *(const uint4*)&cb[lr * CS + (lane & 7) * 8];
            *(uint4*)(C + (size_t)r * NN + bn + (lane & 7) * 8) = val;
        }
    }
}

// ---------------------------------------------------------------- D=64 gather: 2 nodes per wave (32-lane halves)
// softmax over 32 lanes per node; 4 edge-slots of 8 lanes each; 4-deep predicated gather
__global__ __launch_bounds__(256) void gather2_kernel(const u16* __restrict__ X,
                                                      const float* __restrict__ lsld,
                                                      const int* __restrict__ row_ptr,
                                                      const int* __restrict__ col_idx,
                                                      u16* __restrict__ out) {
    __shared__ float2 ec_all[4][64];
    int gw = (blockIdx.x * 256 + threadIdx.x) >> 6;   // wave id (0..24999)
    int lane = threadIdx.x & 63;
    int half = lane >> 5;
    int hl = lane & 31;
    int nid = gw * 2 + half;
    if (nid >= N_NODES) return;
    float2* __restrict__ ec = ec_all[threadIdx.x >> 6] + half * 32;
    const int start = row_ptr[nid];
    const int end = row_ptr[nid + 1];
    const int deg = end - start;
    const float ldi = lsld[N_NODES + nid];
    const float* __restrict__ ls = lsld;
    const int eslot = hl >> 3;   // 0..3
    const int fidx = hl & 7;
    float a[8] = {0.f, 0.f, 0.f, 0.f, 0.f, 0.f, 0.f, 0.f};

    auto fma8 = [&](float cc, uint4 v) {
        a[0] += cc * b2f_lo(v.x); a[1] += cc * b2f_hi(v.x);
        a[2] += cc * b2f_lo(v.y); a[3] += cc * b2f_hi(v.y);
        a[4] += cc * b2f_lo(v.z); a[5] += cc * b2f_hi(v.z);
        a[6] += cc * b2f_lo(v.w); a[7] += cc * b2f_hi(v.w);
    };

    if (deg <= 32) {
        // softmax in registers (edge ordinal == hl), stage (coef, src) to LDS
        int srcl = 0;
        float l = -3.0e38f;
        if (hl < deg) {
            srcl = col_idx[start + hl];
            float t = ls[srcl] + ldi;
            l = (t > 0.f) ? t : 0.2f * t;
        }
        float m = l;
#pragma unroll
        for (int off = 16; off > 0; off >>= 1) m = fmaxf(m, __shfl_xor(m, off));
        float e = (hl < deg) ? __expf(l - m) : 0.f;
        float s = e;
#pragma unroll
        for (int off = 16; off > 0; off >>= 1) s += __shfl_xor(s, off);
        ec[hl] = make_float2(e / s, __int_as_float(srcl));
        // wave-synchronous: ds_write -> ds_read ordered within the wave

        const int nsteps = (deg + 3) >> 2;    // 4 edge slots per node
        for (int g0 = 0; g0 < nsteps; g0 += 4) {
            float2 p[4]; uint4 v[4];
#pragma unroll
            for (int j = 0; j < 4; ++j) {
                int idx = (g0 + j) * 4 + eslot;
                bool valid = idx < deg;
                p[j] = ec[valid ? idx : 0];
                if (!valid) p[j].x = 0.f;
            }
#pragma unroll
            for (int j = 0; j < 4; ++j)
                v[j] = *(const uint4*)(X + (size_t)__float_as_int(p[j].y) * 64 + fidx * 8);
#pragma unroll
            for (int j = 0; j < 4; ++j) fma8(p[j].x, v[j]);
        }
    } else {
        // deg > 32: strided 32-lane passes, recompute coef during gather
        float m = -3.0e38f;
        for (int e = start + hl; e < end; e += 32) {
            float t = ls[col_idx[e]] + ldi;
            t = (t > 0.f) ? t : 0.2f * t;
            m = fmaxf(m, t);
        }
#pragma unroll
        for (int off = 16; off > 0; off >>= 1) m = fmaxf(m, __shfl_xor(m, off));
        float ssum = 0.f;
        for (int e = start + hl; e < end; e += 32) {
            float t = ls[col_idx[e]] + ldi;
            t = (t > 0.f) ? t : 0.2f * t;
            ssum += __expf(t - m);
        }
#pragma unroll
        for (int off = 16; off > 0; off >>= 1) ssum += __shfl_xor(ssum, off);
        const float inv = 1.0f / ssum;
        for (int e0 = start; e0 < end; e0 += 4) {
            int e = e0 + eslot;
            if (e < end) {
                int src = col_idx[e];
                float t = ls[src] + ldi;
                t = (t > 0.f) ? t : 0.2f * t;
                float cc = __expf(t - m) * inv;
                uint4 v = *(const uint4*)(X + (size_t)src * 64 + fidx * 8);
                fma8(cc, v);
            }
        }
    }
    // reduce across the 4 edge slots (xor 8, 16 stay within the 32-half)
#pragma unroll
    for (int mm = 8; mm < 32; mm <<= 1) {
#pragma unroll
        for (int i = 0; i < 8; ++i) a[i] += __shfl_xor(a[i], mm);
    }
    if (hl < 8) {
        uint4 o;
        o.x = f2b(a[0]) | (f2b(a[1]) << 16);
        o.y = f2b(a[2]) | (f2b(a[3]) << 16);
        o.z = f2b(a[4]) | (f2b(a[5]) << 16);
        o.w = f2b(a[6]) | (f2b(a[7]) << 16);
        *(uint4*)(out + (size_t)nid * 64 + hl * 8) = o;
    }
}

// ---------------------------------------------------------------- D=128 gather (wave per node, 4-deep predicated)
template <int D>
__global__ __launch_bounds__(256) void gather_fused_kernel(const u16* __restrict__ X,
                                                           const float* __restrict__ lsld,
                                                           const int* __restrict__ row_ptr,
                                                           const int* __restrict__ col_idx,
                                                           u16* __restrict__ out) {
    constexpr int L = D / 8;     // lanes per edge (16B = 8 bf16 each)
    constexpr int P = 64 / L;    // edges handled concurrently by one wave
    __shared__ float2 ec_all[4][64];
    int wid = (blockIdx.x * 256 + threadIdx.x) >> 6;
    int lane = threadIdx.x & 63;
    if (wid >= N_NODES) return;
    float2* __restrict__ ec = ec_all[threadIdx.x >> 6];
    const int start = row_ptr[wid];
    const int end = row_ptr[wid + 1];
    const int deg = end - start;
    const float ldi = lsld[N_NODES + wid];
    const float* __restrict__ ls = lsld;
    const int eslot = lane / L;
    const int fidx = lane % L;
    float a[8] = {0.f, 0.f, 0.f, 0.f, 0.f, 0.f, 0.f, 0.f};

    auto fma8 = [&](float cc, uint4 v) {
        a[0] += cc * b2f_lo(v.x); a[1] += cc * b2f_hi(v.x);
        a[2] += cc * b2f_lo(v.y); a[3] += cc * b2f_hi(v.y);
        a[4] += cc * b2f_lo(v.z); a[5] += cc * b2f_hi(v.z);
        a[6] += cc * b2f_lo(v.w); a[7] += cc * b2f_hi(v.w);
    };

    if (deg <= 64) {
        int srcl = 0;
        float l = -3.0e38f;
        if (lane < deg) {
            srcl = col_idx[start + lane];
            float t = ls[srcl] + ldi;
            l = (t > 0.f) ? t : 0.2f * t;
        }
        float m = l;
#pragma unroll
        for (int off = 32; off > 0; off >>= 1) m = fmaxf(m, __shfl_xor(m, off));
        float e = (lane < deg) ? __expf(l - m) : 0.f;
        float s = e;
#pragma unroll
        for (int off = 32; off > 0; off >>= 1) s += __shfl_xor(s, off);
        ec[lane] = make_float2(e / s, __int_as_float(srcl));
        // wave-synchronous: ds_write -> ds_read ordered within the wave

        const int nsteps = (deg + P - 1) / P;
        for (int g0 = 0; g0 < nsteps; g0 += 4) {
            float2 p[4]; uint4 v[4];
#pragma unroll
            for (int j = 0; j < 4; ++j) {
                int idx = (g0 + j) * P + eslot;
                bool valid = idx < deg;
                p[j] = ec[valid ? idx : 0];
                if (!valid) p[j].x = 0.f;
            }
#pragma unroll
            for (int j = 0; j < 4; ++j)
                v[j] = *(const uint4*)(X + (size_t)__float_as_int(p[j].y) * D + fidx * 8);
#pragma unroll
            for (int j = 0; j < 4; ++j) fma8(p[j].x, v[j]);
        }
    } else {
        float m = -3.0e38f;
        for (int e = start + lane; e < end; e += 64) {
            float t = ls[col_idx[e]] + ldi;
            t = (t > 0.f) ? t : 0.2f * t;
            m = fmaxf(m, t);
        }
#pragma unroll
        for (int off = 32; off > 0; off >>= 1) m = fmaxf(m, __shfl_xor(m, off));
        float ssum = 0.f;
        for (int e = start + lane; e < end; e += 64) {
            float t = ls[col_idx[e]] + ldi;
            t = (t > 0.f) ? t : 0.2f * t;
            ssum += __expf(t - m);
        }
#pragma unroll
        for (int off = 32; off > 0; off >>= 1) ssum += __shfl_xor(ssum, off);
        const float inv = 1.0f / ssum;
        for (int e0 = start; e0 < end; e0 += P) {
            int e = e0 + eslot;
            if (e < end) {
                int src = col_idx[e];
                float t = ls[src] + ldi;
                t = (t > 0.f) ? t : 0.2f * t;
                float cc = __expf(t - m) * inv;
                uint4 v = *(const uint4*)(X + (size_t)src * D + fidx * 8);
                fma8(cc, v);
            }
        }
    }
#pragma unroll
    for (int mm = L; mm < 64; mm <<= 1) {
#pragma unroll
        for (int i = 0; i < 8; ++i) a[i] += __shfl_xor(a[i], mm);
    }
    if (lane < L) {
        uint4 o;
        o.x = f2b(a[0]) | (f2b(a[1]) << 16);
        o.y = f2b(a[2]) | (f2b(a[3]) << 16);
        o.z = f2b(a[4]) | (f2b(a[5]) << 16);
        o.w = f2b(a[6]) | (f2b(a[7]) << 16);
        *(uint4*)(out + (size_t)wid * D + lane * 8) = o;
    }
}

// ---------------------------------------------------------------- merged head MLP (gcnt + fc1 + fc2, f32)
__device__ inline int lower_bound_dev(const int* __restrict__ a, int n, int v) {
    int lo = 0, hi = n;
    while (lo < hi) { int mid = (lo + hi) >> 1; if (a[mid] < v) lo = mid + 1; else hi = mid; }
    return lo;
}

__global__ __launch_bounds__(256) void fc_kernel(const float* __restrict__ gsum,
                                                 const int* __restrict__ batch,
                                                 const float* __restrict__ w1,
                                                 const float* __restrict__ b1,
                                                 const float* __restrict__ w2,
                                                 const float* __restrict__ b2,
                                                 float* __restrict__ out) {
    __shared__ float gc[256];
    __shared__ float h1s[HID];
    __shared__ float red[256];
    __shared__ int s_cnt;
    int g = blockIdx.x;
    int tid = threadIdx.x;
    if (tid == 0)
        s_cnt = lower_bound_dev(batch, N_NODES, g + 1) - lower_bound_dev(batch, N_NODES, g);
    __syncthreads();
    float denom = fmaxf((float)s_cnt, 1.0f);
    gc[tid] = gsum[g * 256 + tid] / denom;
    __syncthreads();
#pragma unroll
    for (int jj = 0; jj < 2; ++jj) {
        int j = tid + jj * 256;
        float sum = b1[j];
        for (int k = 0; k < 256; ++k) sum += gc[k] * w1[k * HID + j];
        h1s[j] = (sum > 0.f) ? sum : 0.f;
    }
    __syncthreads();
    float acc = h1s[tid] * w2[tid] + h1s[tid + 256] * w2[tid + 256];
    red[tid] = acc;
    __syncthreads();
    for (int off = 128; off > 0; off >>= 1) {
        if (tid < off) red[tid] += red[tid + off];
        __syncthreads();
    }
    if (tid == 0) out[g] = red[0] + b2[0];
}

// ---------------------------------------------------------------- launch
extern "C" void kernel_launch(void* const* d_in, const int* in_sizes, int n_in,
                              void* d_out, int out_size, void* d_ws, size_t ws_size,
                              hipStream_t stream) {
    const float* feature  = (const float*)d_in[0];
    const int*   edge_idx = (const int*)d_in[1];
    const int*   batch    = (const int*)d_in[2];
    const float* W1    = (const float*)d_in[3];
    const float* att1  = (const float*)d_in[4];
    const float* b1    = (const float*)d_in[5];
    const float* W2    = (const float*)d_in[6];
    const float* att2  = (const float*)d_in[7];
    const float* b2    = (const float*)d_in[8];
    const float* W3    = (const float*)d_in[9];
    const float* att3  = (const float*)d_in[10];
    const float* b3    = (const float*)d_in[11];
    const float* fc1_w = (const float*)d_in[12];
    const float* fc1_b = (const float*)d_in[13];
    const float* fc2_w = (const float*)d_in[14];
    const float* fc2_b = (const float*)d_in[15];
    float* out = (float*)d_out;

    char* w = (char*)d_ws;
    auto alloc = [&](size_t bytes) {
        char* p = w;
        w += (bytes + 255) & ~(size_t)255;
        return p;
    };
    u16* Fb    = (u16*)alloc((size_t)N_NODES * 64 * 2);
    u16* X1b   = (u16*)alloc((size_t)N_NODES * 64 * 2);
    u16* X2b   = (u16*)alloc((size_t)N_NODES * 128 * 2);
    u16* AGGb  = (u16*)alloc((size_t)N_NODES * 128 * 2);
    float* lsld1 = (float*)alloc((size_t)N_NODES * 2 * 4);
    // ---- contiguous zero region: cnt | gsum | lsld2 | lsld3 ----
    char* zbase = w;
    int* cnt      = (int*)alloc((size_t)N_NODES * 4);
    float* gsum   = (float*)alloc(64 * 256 * 4);
    float* lsld23 = (float*)alloc((size_t)N_NODES * 4 * 4);
    size_t zbytes = (size_t)(w - zbase);
    float* lsld2 = lsld23;
    float* lsld3 = lsld23 + (size_t)N_NODES * 2;
    // ---------------------------------------------------------------
    float* wsd1  = (float*)alloc(2 * 64 * 4);
    float* wsd2  = (float*)alloc(2 * 64 * 4);
    float* wsd3  = (float*)alloc(2 * 128 * 4);
    u16* Wt1   = (u16*)alloc(64 * 64 * 2);     // [Dout,Din]
    u16* Wt2   = (u16*)alloc(128 * 64 * 2);
    u16* Wt3   = (u16*)alloc(256 * 128 * 2);
    int* row_ptr  = (int*)alloc((size_t)N_NODES * 4);        // partial (block-local)
    int* row_ptr2 = (int*)alloc((size_t)(N_NODES + 1) * 4);  // finalized
    int* col_idx  = (int*)alloc((size_t)E_TOT * 4);
    int* order    = (int*)alloc((size_t)E_TOT * 4);
    int* blocksum = (int*)alloc(256 * 4);

    hipMemsetAsync(zbase, 0, zbytes, stream);

    const int GB = (N_NODES + 127) / 128;        // MFMA GEMM row-blocks (391)

    PrepDesc pd;
    pd.W[0] = W1; pd.W[1] = W2; pd.W[2] = W3;
    pd.att[0] = att1; pd.att[1] = att2; pd.att[2] = att3;
    pd.wsd[0] = wsd1; pd.wsd[1] = wsd2; pd.wsd[2] = wsd3;
    pd.Wt[0] = Wt1; pd.Wt[1] = Wt2; pd.Wt[2] = Wt3;

    // D1: prep + CSR count (independent halves)
    prep_count_kernel<<<PB + EB, 256, 0, stream>>>(pd, edge_idx + N_EDGES, cnt, order);
    // D2: block-local scan + feature cvt/lsld1 (independent halves)
    scan_cvt_kernel<<<NBC + WB, 256, 0, stream>>>(cnt, row_ptr, blocksum, feature, wsd1, Fb, lsld1);
    // D3: row_ptr finalize + scatter fill (per-block redundant blocksum scan)
    fin_fill_kernel<<<NBC + EB, 256, 0, stream>>>(edge_idx, row_ptr, blocksum, order, col_idx, row_ptr2);

    // ---- layer 1: Din=64 -> Dout=64
    gather2_kernel<<<WB2, 256, 0, stream>>>(Fb, lsld1, row_ptr2, col_idx, AGGb);
    sgemm_mfma_kernel<64, 64><<<dim3(GB, 1), 256, 0, stream>>>(AGGb, Wt1, X1b, b1, wsd2, lsld2, nullptr, nullptr, N_NODES);

    // ---- layer 2: Din=64 -> Dout=128
    gather2_kernel<<<WB2, 256, 0, stream>>>(X1b, lsld2, row_ptr2, col_idx, AGGb);
    sgemm_mfma_kernel<128, 64><<<dim3(GB, 2), 256, 0, stream>>>(AGGb, Wt2, X2b, b2, wsd3, lsld3, nullptr, nullptr, N_NODES);

    // ---- layer 3: Din=128 -> Dout=256, fused mean-pool numerator (no X3 materialization)
    gather_fused_kernel<128><<<WB, 256, 0, stream>>>(X2b, lsld3, row_ptr2, col_idx, AGGb);
    sgemm_mfma_kernel<256, 128><<<dim3(GB, 4), 256, 0, stream>>>(AGGb, Wt3, nullptr, b3, nullptr, nullptr, batch, gsum, N_NODES);

    // ---- merged head (gcnt + fc1 + fc2)
    fc_kernel<<<N_GRAPHS, 256, 0, stream>>>(gsum, batch, fc1_w, fc1_b, fc2_w, fc2_b, out);
}